// Round 1
// baseline (399.016 us; speedup 1.0000x reference)
//
#include <hip/hip_runtime.h>
#include <hip/hip_bf16.h>

#define BDIM 96
#define TDIM 96
#define KREP 10
#define KD 960
#define IN3 288
#define BT 1536   // 16*96
#define NB 16

__device__ __forceinline__ float tanh_fast(float x) {
    x = fminf(fmaxf(x, -15.f), 15.f);
    float e = __expf(2.f * x);
    return __fdividef(e - 1.f, e + 1.f);
}

// ---------------- concat [X, M, deltas_f] -> inp (BT,288) ----------------
__global__ __launch_bounds__(256) void concat_kernel(
    const float* __restrict__ X, const float* __restrict__ M,
    const float* __restrict__ DF, float* __restrict__ inp) {
    int idx = blockIdx.x * 256 + threadIdx.x;
    if (idx >= BT * IN3) return;
    int m = idx / IN3, j = idx % IN3;
    float v;
    if (j < 96)       v = X[m * 96 + j];
    else if (j < 192) v = M[m * 96 + (j - 96)];
    else              v = DF[m * 96 + (j - 192)];
    inp[idx] = v;
}

// ---------------- tiled fp32 GEMM: C[m,n] = sum_k A[m,k]*B[n,k] ----------------
// EPI==1: += b_e[n] + pos[(m%96)*960+n], then ELU
template <int EPI>
__global__ __launch_bounds__(256) void gemm_nt(
    const float* __restrict__ A, const float* __restrict__ Bm,
    float* __restrict__ C, int Mr, int Nr, int Kd,
    const float* __restrict__ bias, const float* __restrict__ pos) {
    const int BM = 64, BN = 64, BK = 16;
    __shared__ float As[BK][BM + 4];
    __shared__ float Bs[BK][BN + 4];
    int bm = blockIdx.y * BM, bn = blockIdx.x * BN;
    int tid = threadIdx.x;
    int tn = (tid % 16) * 4;
    int tm = (tid / 16) * 4;
    float acc[4][4] = {};
    int r = tid / 4, c = (tid % 4) * 4;
    for (int k0 = 0; k0 < Kd; k0 += BK) {
        float4 av = *(const float4*)(A + (size_t)(bm + r) * Kd + k0 + c);
        float4 bv = *(const float4*)(Bm + (size_t)(bn + r) * Kd + k0 + c);
        As[c + 0][r] = av.x; As[c + 1][r] = av.y; As[c + 2][r] = av.z; As[c + 3][r] = av.w;
        Bs[c + 0][r] = bv.x; Bs[c + 1][r] = bv.y; Bs[c + 2][r] = bv.z; Bs[c + 3][r] = bv.w;
        __syncthreads();
#pragma unroll
        for (int kk = 0; kk < BK; kk++) {
            float4 a = *(const float4*)&As[kk][tm];
            float4 b = *(const float4*)&Bs[kk][tn];
            acc[0][0] += a.x * b.x; acc[0][1] += a.x * b.y; acc[0][2] += a.x * b.z; acc[0][3] += a.x * b.w;
            acc[1][0] += a.y * b.x; acc[1][1] += a.y * b.y; acc[1][2] += a.y * b.z; acc[1][3] += a.y * b.w;
            acc[2][0] += a.z * b.x; acc[2][1] += a.z * b.y; acc[2][2] += a.z * b.z; acc[2][3] += a.z * b.w;
            acc[3][0] += a.w * b.x; acc[3][1] += a.w * b.y; acc[3][2] += a.w * b.z; acc[3][3] += a.w * b.w;
        }
        __syncthreads();
    }
#pragma unroll
    for (int i = 0; i < 4; i++) {
        int m = bm + tm + i;
        int t = m % 96;
        float4 o;
        float* po = (float*)&o;
#pragma unroll
        for (int j = 0; j < 4; j++) {
            int n = bn + tn + j;
            float x = acc[i][j];
            if (EPI == 1) {
                x += bias[n] + pos[t * KD + n];
                x = x > 0.f ? x : (__expf(x) - 1.f);
            }
            po[j] = x;
        }
        *(float4*)(C + (size_t)m * Nr + bn + tn) = o;
    }
}

// ---------------- fused attention: logits(tanh) -> softmax -> h_a ----------------
// one block per (b, 4 query rows)
__global__ __launch_bounds__(256) void attn_kernel(
    const float* __restrict__ key_v, const float* __restrict__ qry_v,
    const float* __restrict__ h_e, const float* __restrict__ w_a,
    float* __restrict__ h_a) {
    __shared__ float q_s[4][KD];
    __shared__ float w_s[KD];
    __shared__ float logit_s[4][96];
    int b = blockIdx.x / 24;
    int i0 = (blockIdx.x % 24) * 4;
    int tid = threadIdx.x;
    int lane = tid & 63;
    int wv = tid >> 6;  // 4 waves

    const float* qb = qry_v + ((size_t)b * 96 + i0) * KD;
    for (int x = tid; x < 4 * KD; x += 256) q_s[x / KD][x % KD] = qb[x];
    for (int x = tid; x < KD; x += 256) w_s[x] = w_a[x];
    __syncthreads();

    // logits: wave wv handles j = wv, wv+4, ...; 4 query rows at once
    for (int j = wv; j < 96; j += 4) {
        const float* kp = key_v + ((size_t)b * 96 + j) * KD;
        float s0 = 0.f, s1 = 0.f, s2 = 0.f, s3 = 0.f;
        for (int d = lane; d < KD; d += 64) {
            float kd = kp[d], wd = w_s[d];
            s0 += wd * tanh_fast(kd + q_s[0][d]);
            s1 += wd * tanh_fast(kd + q_s[1][d]);
            s2 += wd * tanh_fast(kd + q_s[2][d]);
            s3 += wd * tanh_fast(kd + q_s[3][d]);
        }
#pragma unroll
        for (int off = 32; off; off >>= 1) {
            s0 += __shfl_down(s0, off);
            s1 += __shfl_down(s1, off);
            s2 += __shfl_down(s2, off);
            s3 += __shfl_down(s3, off);
        }
        if (lane == 0) {
            logit_s[0][j] = s0; logit_s[1][j] = s1; logit_s[2][j] = s2; logit_s[3][j] = s3;
        }
    }
    __syncthreads();

    // softmax over j (96) — wave wv owns row wv
    {
        float x0 = logit_s[wv][lane];
        float x1 = (lane < 32) ? logit_s[wv][lane + 64] : -1e30f;
        float mx = fmaxf(x0, x1);
#pragma unroll
        for (int off = 32; off; off >>= 1) mx = fmaxf(mx, __shfl_xor(mx, off));
        float e0 = __expf(x0 - mx);
        float e1 = (lane < 32) ? __expf(x1 - mx) : 0.f;
        float sm = e0 + e1;
#pragma unroll
        for (int off = 32; off; off >>= 1) sm += __shfl_xor(sm, off);
        float inv = __fdividef(1.f, sm);
        logit_s[wv][lane] = e0 * inv;
        if (lane < 32) logit_s[wv][lane + 64] = e1 * inv;
    }
    __syncthreads();

    // h_a rows: each thread owns dims d, accumulates 4 rows simultaneously
    for (int d = tid; d < KD; d += 256) {
        const float* hp = h_e + (size_t)b * 96 * KD + d;
        float a0 = 0.f, a1 = 0.f, a2 = 0.f, a3 = 0.f;
#pragma unroll 4
        for (int j = 0; j < 96; j++) {
            float he = hp[(size_t)j * KD];
            a0 += logit_s[0][j] * he;
            a1 += logit_s[1][j] * he;
            a2 += logit_s[2][j] * he;
            a3 += logit_s[3][j] * he;
        }
        float* op = h_a + ((size_t)b * 96 + i0) * KD + d;
        op[0 * KD] = a0; op[1 * KD] = a1; op[2 * KD] = a2; op[3 * KD] = a3;
    }
}

// ---------------- temporal decay ----------------
__global__ __launch_bounds__(256) void decay_kernel(
    const float* __restrict__ h_a, const float* __restrict__ M,
    const float* __restrict__ DF, const float* __restrict__ W_td,
    const float* __restrict__ b_td, float* __restrict__ h_r) {
    int idx = blockIdx.x * 256 + threadIdx.x;
    if (idx >= BT * KD) return;
    int bt = idx / KD, kd = idx % KD;
    int d = kd % 96;
    int t = bt % 96;
    float m = M[bt * 96 + d];
    float dl = DF[bt * 96 + d];
    float g = __expf(-fmaxf(dl * W_td[kd] + b_td[kd], 0.f));
    int tsrc = t - (int)dl + 1;
    float ha = h_a[idx];
    float hf = h_a[(size_t)(bt - t + tsrc) * KD + kd];
    h_r[idx] = m * ha + (1.f - m) * (g * hf + (1.f - g) * ha);
}

// ---------------- imputation ----------------
__global__ __launch_bounds__(256) void imput_kernel(
    const float* __restrict__ h_r, const float* __restrict__ W_imp,
    const float* __restrict__ b_imp, float* __restrict__ imput) {
    int idx = blockIdx.x * 256 + threadIdx.x;
    if (idx >= BT * 96) return;
    int bt = idx / 96, d = idx % 96;
    float s = b_imp[d];
#pragma unroll
    for (int k = 0; k < KREP; k++)
        s += W_imp[d * KD + k * 96 + d] * h_r[(size_t)bt * KD + k * 96 + d];
    imput[idx] = s;
}

// ---------------- dense interpolation: v[b,kd,f] = sum_t Wi[f,t]*h_r[b,t,kd] ----------------
__global__ __launch_bounds__(256) void vinterp_kernel(
    const float* __restrict__ h_r, float* __restrict__ v) {
    int idx = blockIdx.x * 256 + threadIdx.x;
    if (idx >= NB * KD) return;
    int b = idx / KD, kd = idx % KD;
    const float* hp = h_r + (size_t)b * 96 * KD + kd;
    float a0 = 0.f, a1 = 0.f, a2 = 0.f;
    for (int t = 0; t < 96; t++) {
        float h = hp[(size_t)t * KD];
        float p = 3.f * (t + 1) * (1.f / 96.f);
        float w0 = 1.f - fabsf(p - 1.f) * (1.f / 3.f);
        float w1 = 1.f - fabsf(p - 2.f) * (1.f / 3.f);
        float w2 = 1.f - fabsf(p - 3.f) * (1.f / 3.f);
        a0 += w0 * w0 * h; a1 += w1 * w1 * h; a2 += w2 * w2 * h;
    }
    float* vp = v + (size_t)b * 2880 + kd * 3;
    vp[0] = a0; vp[1] = a1; vp[2] = a2;
}

// ---------------- final FC: out[b,o] ----------------
__global__ __launch_bounds__(64) void fc_kernel(
    const float* __restrict__ v, const float* __restrict__ W_fc,
    const float* __restrict__ b_fc, float* __restrict__ out) {
    int b = blockIdx.x / 10, o = blockIdx.x % 10;
    int lane = threadIdx.x;
    const float* vp = v + (size_t)b * 2880;
    const float* wp = W_fc + (size_t)o * 2880;
    float s = 0.f;
    for (int j = lane; j < 2880; j += 64) s += vp[j] * wp[j];
#pragma unroll
    for (int off = 32; off; off >>= 1) s += __shfl_down(s, off);
    if (lane == 0) out[b * 10 + o] = s + b_fc[o];
}

extern "C" void kernel_launch(void* const* d_in, const int* in_sizes, int n_in,
                              void* d_out, int out_size, void* d_ws, size_t ws_size,
                              hipStream_t stream) {
    const float* X    = (const float*)d_in[0];
    const float* M    = (const float*)d_in[1];
    const float* DF   = (const float*)d_in[2];
    const float* W_e  = (const float*)d_in[3];
    const float* b_e  = (const float*)d_in[4];
    const float* pos  = (const float*)d_in[5];
    const float* W_a  = (const float*)d_in[6];
    const float* V_a  = (const float*)d_in[7];
    const float* w_a  = (const float*)d_in[8];
    const float* W_td = (const float*)d_in[9];
    const float* b_td = (const float*)d_in[10];
    const float* W_imp= (const float*)d_in[11];
    const float* b_imp= (const float*)d_in[12];
    const float* W_fc = (const float*)d_in[13];
    const float* b_fc = (const float*)d_in[14];

    float* out   = (float*)d_out;         // (16,10)
    float* imput = (float*)d_out + 160;   // (16,96,96)

    float* ws   = (float*)d_ws;
    float* inp  = ws;                     // 1536*288
    float* h_e  = inp + (size_t)BT * IN3; // 1536*960
    float* keyv = h_e + (size_t)BT * KD;
    float* qryv = keyv + (size_t)BT * KD;
    float* ha   = qryv + (size_t)BT * KD;
    float* hr   = ha + (size_t)BT * KD;
    float* vv   = hr + (size_t)BT * KD;   // 16*2880

    concat_kernel<<<(BT * IN3 + 255) / 256, 256, 0, stream>>>(X, M, DF, inp);
    gemm_nt<1><<<dim3(15, 24), 256, 0, stream>>>(inp, W_e, h_e, BT, KD, IN3, b_e, pos);
    gemm_nt<0><<<dim3(15, 24), 256, 0, stream>>>(h_e, W_a, keyv, BT, KD, KD, nullptr, nullptr);
    gemm_nt<0><<<dim3(15, 24), 256, 0, stream>>>(h_e, V_a, qryv, BT, KD, KD, nullptr, nullptr);
    attn_kernel<<<NB * 24, 256, 0, stream>>>(keyv, qryv, h_e, w_a, ha);
    decay_kernel<<<(BT * KD + 255) / 256, 256, 0, stream>>>(ha, M, DF, W_td, b_td, hr);
    imput_kernel<<<(BT * 96 + 255) / 256, 256, 0, stream>>>(hr, W_imp, b_imp, imput);
    vinterp_kernel<<<(NB * KD + 255) / 256, 256, 0, stream>>>(hr, vv);
    fc_kernel<<<160, 64, 0, stream>>>(vv, W_fc, b_fc, out);
}

// Round 2
// 286.837 us; speedup vs baseline: 1.3911x; 1.3911x over previous
//
#include <hip/hip_runtime.h>
#include <hip/hip_bf16.h>

#define BDIM 96
#define TDIM 96
#define KREP 10
#define KD 960
#define IN3 288
#define BT 1536   // 16*96
#define NB 16

// tanh(x) = 1 - 2/(exp2(2*log2e*x)+1); saturates correctly at +-inf, no clamp.
__device__ __forceinline__ float tanh_fast(float x) {
    float e2 = exp2f(x * 2.885390081777927f);   // e^(2x)
    float r = __builtin_amdgcn_rcpf(e2 + 1.f);
    return __builtin_fmaf(-2.f, r, 1.f);
}

// ---------------- concat [X, M, deltas_f] -> inp (BT,288) ----------------
__global__ __launch_bounds__(256) void concat_kernel(
    const float* __restrict__ X, const float* __restrict__ M,
    const float* __restrict__ DF, float* __restrict__ inp) {
    int idx = blockIdx.x * 256 + threadIdx.x;
    if (idx >= BT * IN3) return;
    int m = idx / IN3, j = idx % IN3;
    float v;
    if (j < 96)       v = X[m * 96 + j];
    else if (j < 192) v = M[m * 96 + (j - 96)];
    else              v = DF[m * 96 + (j - 192)];
    inp[idx] = v;
}

// ---------------- tiled fp32 GEMM: C[m,n] = sum_k A[m,k]*B[n,k] ----------------
// EPI==1: += b_e[n] + pos[(m%96)*960+n], then ELU
template <int EPI>
__global__ __launch_bounds__(256) void gemm_nt(
    const float* __restrict__ A, const float* __restrict__ Bm,
    float* __restrict__ C, int Mr, int Nr, int Kd,
    const float* __restrict__ bias, const float* __restrict__ pos) {
    const int BM = 64, BN = 64, BK = 16;
    __shared__ float As[BK][BM + 4];
    __shared__ float Bs[BK][BN + 4];
    int bm = blockIdx.y * BM, bn = blockIdx.x * BN;
    int tid = threadIdx.x;
    int tn = (tid % 16) * 4;
    int tm = (tid / 16) * 4;
    float acc[4][4] = {};
    int r = tid / 4, c = (tid % 4) * 4;
    for (int k0 = 0; k0 < Kd; k0 += BK) {
        float4 av = *(const float4*)(A + (size_t)(bm + r) * Kd + k0 + c);
        float4 bv = *(const float4*)(Bm + (size_t)(bn + r) * Kd + k0 + c);
        As[c + 0][r] = av.x; As[c + 1][r] = av.y; As[c + 2][r] = av.z; As[c + 3][r] = av.w;
        Bs[c + 0][r] = bv.x; Bs[c + 1][r] = bv.y; Bs[c + 2][r] = bv.z; Bs[c + 3][r] = bv.w;
        __syncthreads();
#pragma unroll
        for (int kk = 0; kk < BK; kk++) {
            float4 a = *(const float4*)&As[kk][tm];
            float4 b = *(const float4*)&Bs[kk][tn];
            acc[0][0] += a.x * b.x; acc[0][1] += a.x * b.y; acc[0][2] += a.x * b.z; acc[0][3] += a.x * b.w;
            acc[1][0] += a.y * b.x; acc[1][1] += a.y * b.y; acc[1][2] += a.y * b.z; acc[1][3] += a.y * b.w;
            acc[2][0] += a.z * b.x; acc[2][1] += a.z * b.y; acc[2][2] += a.z * b.z; acc[2][3] += a.z * b.w;
            acc[3][0] += a.w * b.x; acc[3][1] += a.w * b.y; acc[3][2] += a.w * b.z; acc[3][3] += a.w * b.w;
        }
        __syncthreads();
    }
#pragma unroll
    for (int i = 0; i < 4; i++) {
        int m = bm + tm + i;
        int t = m % 96;
        float4 o;
        float* po = (float*)&o;
#pragma unroll
        for (int j = 0; j < 4; j++) {
            int n = bn + tn + j;
            float x = acc[i][j];
            if (EPI == 1) {
                x += bias[n] + pos[t * KD + n];
                x = x > 0.f ? x : (__expf(x) - 1.f);
            }
            po[j] = x;
        }
        *(float4*)(C + (size_t)m * Nr + bn + tn) = o;
    }
}

// ---------------- fused attention: logits(tanh) -> softmax -> h_a ----------------
// one block per (b, 4 query rows); 512 threads = 8 waves.
// q and w_a cached in registers (15 strided elems per lane each).
__global__ __launch_bounds__(512) void attn_kernel(
    const float* __restrict__ key_v, const float* __restrict__ qry_v,
    const float* __restrict__ h_e, const float* __restrict__ w_a,
    float* __restrict__ h_a) {
    __shared__ float logit_s[4][96];
    int b = blockIdx.x / 24;
    int i0 = (blockIdx.x % 24) * 4;
    int tid = threadIdx.x;
    int lane = tid & 63;
    int wv = tid >> 6;  // 8 waves

    // register-cache w_a and the 4 query rows (strided: lane owns d = lane+64s)
    float wr[15], qr[4][15];
    const float* qb = qry_v + ((size_t)b * 96 + i0) * KD;
#pragma unroll
    for (int s = 0; s < 15; s++) {
        int d = s * 64 + lane;
        wr[s] = w_a[d];
#pragma unroll
        for (int r = 0; r < 4; r++) qr[r][s] = qb[(size_t)r * KD + d];
    }

    // logits: wave wv handles j = wv, wv+8, ... (12 iters)
    for (int j = wv; j < 96; j += 8) {
        const float* kp = key_v + ((size_t)b * 96 + j) * KD;
        float s0 = 0.f, s1 = 0.f, s2 = 0.f, s3 = 0.f;
#pragma unroll
        for (int s = 0; s < 15; s++) {
            float kd = kp[s * 64 + lane];
            float w = wr[s];
            s0 = __builtin_fmaf(w, tanh_fast(kd + qr[0][s]), s0);
            s1 = __builtin_fmaf(w, tanh_fast(kd + qr[1][s]), s1);
            s2 = __builtin_fmaf(w, tanh_fast(kd + qr[2][s]), s2);
            s3 = __builtin_fmaf(w, tanh_fast(kd + qr[3][s]), s3);
        }
#pragma unroll
        for (int off = 32; off; off >>= 1) {
            s0 += __shfl_down(s0, off);
            s1 += __shfl_down(s1, off);
            s2 += __shfl_down(s2, off);
            s3 += __shfl_down(s3, off);
        }
        if (lane == 0) {
            logit_s[0][j] = s0; logit_s[1][j] = s1; logit_s[2][j] = s2; logit_s[3][j] = s3;
        }
    }
    __syncthreads();

    // softmax over j (96) — waves 0..3 own one row each
    if (wv < 4) {
        float x0 = logit_s[wv][lane];
        float x1 = (lane < 32) ? logit_s[wv][lane + 64] : -1e30f;
        float mx = fmaxf(x0, x1);
#pragma unroll
        for (int off = 32; off; off >>= 1) mx = fmaxf(mx, __shfl_xor(mx, off));
        float e0 = __expf(x0 - mx);
        float e1 = (lane < 32) ? __expf(x1 - mx) : 0.f;
        float sm = e0 + e1;
#pragma unroll
        for (int off = 32; off; off >>= 1) sm += __shfl_xor(sm, off);
        float inv = __fdividef(1.f, sm);
        logit_s[wv][lane] = e0 * inv;
        if (lane < 32) logit_s[wv][lane + 64] = e1 * inv;
    }
    __syncthreads();

    // h_a rows: each thread owns dims d, accumulates 4 rows simultaneously
    for (int d = tid; d < KD; d += 512) {
        const float* hp = h_e + (size_t)b * 96 * KD + d;
        float a0 = 0.f, a1 = 0.f, a2 = 0.f, a3 = 0.f;
#pragma unroll 4
        for (int j = 0; j < 96; j++) {
            float he = hp[(size_t)j * KD];
            a0 += logit_s[0][j] * he;
            a1 += logit_s[1][j] * he;
            a2 += logit_s[2][j] * he;
            a3 += logit_s[3][j] * he;
        }
        float* op = h_a + ((size_t)b * 96 + i0) * KD + d;
        op[0 * KD] = a0; op[1 * KD] = a1; op[2 * KD] = a2; op[3 * KD] = a3;
    }
}

// ---------------- temporal decay ----------------
__global__ __launch_bounds__(256) void decay_kernel(
    const float* __restrict__ h_a, const float* __restrict__ M,
    const float* __restrict__ DF, const float* __restrict__ W_td,
    const float* __restrict__ b_td, float* __restrict__ h_r) {
    int idx = blockIdx.x * 256 + threadIdx.x;
    if (idx >= BT * KD) return;
    int bt = idx / KD, kd = idx % KD;
    int d = kd % 96;
    int t = bt % 96;
    float m = M[bt * 96 + d];
    float dl = DF[bt * 96 + d];
    float g = __expf(-fmaxf(dl * W_td[kd] + b_td[kd], 0.f));
    int tsrc = t - (int)dl + 1;
    float ha = h_a[idx];
    float hf = h_a[(size_t)(bt - t + tsrc) * KD + kd];
    h_r[idx] = m * ha + (1.f - m) * (g * hf + (1.f - g) * ha);
}

// ---------------- imputation ----------------
__global__ __launch_bounds__(256) void imput_kernel(
    const float* __restrict__ h_r, const float* __restrict__ W_imp,
    const float* __restrict__ b_imp, float* __restrict__ imput) {
    int idx = blockIdx.x * 256 + threadIdx.x;
    if (idx >= BT * 96) return;
    int bt = idx / 96, d = idx % 96;
    float s = b_imp[d];
#pragma unroll
    for (int k = 0; k < KREP; k++)
        s += W_imp[d * KD + k * 96 + d] * h_r[(size_t)bt * KD + k * 96 + d];
    imput[idx] = s;
}

// ---------------- dense interpolation: v[b,kd,f] = sum_t Wi[f,t]*h_r[b,t,kd] ----------------
__global__ __launch_bounds__(256) void vinterp_kernel(
    const float* __restrict__ h_r, float* __restrict__ v) {
    int idx = blockIdx.x * 256 + threadIdx.x;
    if (idx >= NB * KD) return;
    int b = idx / KD, kd = idx % KD;
    const float* hp = h_r + (size_t)b * 96 * KD + kd;
    float a0 = 0.f, a1 = 0.f, a2 = 0.f;
    for (int t = 0; t < 96; t++) {
        float h = hp[(size_t)t * KD];
        float p = 3.f * (t + 1) * (1.f / 96.f);
        float w0 = 1.f - fabsf(p - 1.f) * (1.f / 3.f);
        float w1 = 1.f - fabsf(p - 2.f) * (1.f / 3.f);
        float w2 = 1.f - fabsf(p - 3.f) * (1.f / 3.f);
        a0 += w0 * w0 * h; a1 += w1 * w1 * h; a2 += w2 * w2 * h;
    }
    float* vp = v + (size_t)b * 2880 + kd * 3;
    vp[0] = a0; vp[1] = a1; vp[2] = a2;
}

// ---------------- final FC: out[b,o] ----------------
__global__ __launch_bounds__(64) void fc_kernel(
    const float* __restrict__ v, const float* __restrict__ W_fc,
    const float* __restrict__ b_fc, float* __restrict__ out) {
    int b = blockIdx.x / 10, o = blockIdx.x % 10;
    int lane = threadIdx.x;
    const float* vp = v + (size_t)b * 2880;
    const float* wp = W_fc + (size_t)o * 2880;
    float s = 0.f;
    for (int j = lane; j < 2880; j += 64) s += vp[j] * wp[j];
#pragma unroll
    for (int off = 32; off; off >>= 1) s += __shfl_down(s, off);
    if (lane == 0) out[b * 10 + o] = s + b_fc[o];
}

extern "C" void kernel_launch(void* const* d_in, const int* in_sizes, int n_in,
                              void* d_out, int out_size, void* d_ws, size_t ws_size,
                              hipStream_t stream) {
    const float* X    = (const float*)d_in[0];
    const float* M    = (const float*)d_in[1];
    const float* DF   = (const float*)d_in[2];
    const float* W_e  = (const float*)d_in[3];
    const float* b_e  = (const float*)d_in[4];
    const float* pos  = (const float*)d_in[5];
    const float* W_a  = (const float*)d_in[6];
    const float* V_a  = (const float*)d_in[7];
    const float* w_a  = (const float*)d_in[8];
    const float* W_td = (const float*)d_in[9];
    const float* b_td = (const float*)d_in[10];
    const float* W_imp= (const float*)d_in[11];
    const float* b_imp= (const float*)d_in[12];
    const float* W_fc = (const float*)d_in[13];
    const float* b_fc = (const float*)d_in[14];

    float* out   = (float*)d_out;         // (16,10)
    float* imput = (float*)d_out + 160;   // (16,96,96)

    float* ws   = (float*)d_ws;
    float* inp  = ws;                     // 1536*288
    float* h_e  = inp + (size_t)BT * IN3; // 1536*960
    float* keyv = h_e + (size_t)BT * KD;
    float* qryv = keyv + (size_t)BT * KD;
    float* ha   = qryv + (size_t)BT * KD;
    float* hr   = ha + (size_t)BT * KD;
    float* vv   = hr + (size_t)BT * KD;   // 16*2880

    concat_kernel<<<(BT * IN3 + 255) / 256, 256, 0, stream>>>(X, M, DF, inp);
    gemm_nt<1><<<dim3(15, 24), 256, 0, stream>>>(inp, W_e, h_e, BT, KD, IN3, b_e, pos);
    gemm_nt<0><<<dim3(15, 24), 256, 0, stream>>>(h_e, W_a, keyv, BT, KD, KD, nullptr, nullptr);
    gemm_nt<0><<<dim3(15, 24), 256, 0, stream>>>(h_e, V_a, qryv, BT, KD, KD, nullptr, nullptr);
    attn_kernel<<<NB * 24, 512, 0, stream>>>(keyv, qryv, h_e, w_a, ha);
    decay_kernel<<<(BT * KD + 255) / 256, 256, 0, stream>>>(ha, M, DF, W_td, b_td, hr);
    imput_kernel<<<(BT * 96 + 255) / 256, 256, 0, stream>>>(hr, W_imp, b_imp, imput);
    vinterp_kernel<<<(NB * KD + 255) / 256, 256, 0, stream>>>(hr, vv);
    fc_kernel<<<160, 64, 0, stream>>>(vv, W_fc, b_fc, out);
}

// Round 3
// 159.453 us; speedup vs baseline: 2.5024x; 1.7989x over previous
//
#include <hip/hip_runtime.h>
#include <hip/hip_bf16.h>

#define KREP 10
#define KD 960
#define BT 1536   // 16*96
#define NB 16

typedef __attribute__((ext_vector_type(8))) short bf16x8;
typedef __attribute__((ext_vector_type(4))) float f32x4;

#define MFMA_16x16x32_BF16 __builtin_amdgcn_mfma_f32_16x16x32_bf16

// ---------------- concat [X, M, deltas_f, 0pad] -> inp_bf16 (BT,320) ----------------
__global__ __launch_bounds__(256) void concat_bf16_kernel(
    const float* __restrict__ X, const float* __restrict__ M,
    const float* __restrict__ DF, __hip_bfloat16* __restrict__ inp) {
    int idx = blockIdx.x * 256 + threadIdx.x;
    if (idx >= BT * 320) return;
    int m = idx / 320, j = idx % 320;
    float v = 0.f;
    if (j < 96)       v = X[m * 96 + j];
    else if (j < 192) v = M[m * 96 + (j - 96)];
    else if (j < 288) v = DF[m * 96 + (j - 192)];
    inp[idx] = __float2bfloat16(v);
}

// ---------------- fp32 -> bf16 with column zero-pad ----------------
__global__ __launch_bounds__(256) void cvt_pad_kernel(
    const float* __restrict__ src, __hip_bfloat16* __restrict__ dst,
    int rows, int cols, int colspad) {
    int idx = blockIdx.x * 256 + threadIdx.x;
    if (idx >= rows * colspad) return;
    int r = idx / colspad, c = idx % colspad;
    float v = (c < cols) ? src[r * cols + c] : 0.f;
    dst[idx] = __float2bfloat16(v);
}

// ---------------- MFMA GEMM helpers (guide m97 pattern, BK=64, XOR-swizzled LDS) ----
// Stage a 64-row x 64-bf16 (128B) tile: linear LDS dest, inverse-swizzled global src.
__device__ __forceinline__ void stage64(const char* gRow0, int ldbytes,
                                        char* ldsTile, int wv, int lane) {
#pragma unroll
    for (int rd = 0; rd < 2; rd++) {
        int c  = rd * 256 + wv * 64 + lane;
        int r  = c >> 3;
        int sl = c & 7;
        int ss = sl ^ (r & 7);
        const char* g = gRow0 + (size_t)r * ldbytes + ss * 16;
        __builtin_amdgcn_global_load_lds((const void*)g,
            (void*)(ldsTile + rd * 4096 + wv * 1024), 16, 0, 0);
    }
}
// Read one A/B fragment (8 contiguous k-elems) with the matching swizzle.
__device__ __forceinline__ bf16x8 ldfrag(const char* lds, int row, int slot) {
    int ss = slot ^ (row & 7);
    return *(const bf16x8*)(lds + row * 128 + ss * 16);
}

// ---------------- embed: h_e = ELU(inp @ W_e^T + b_e + pos); K=320 (padded) --------
__global__ __launch_bounds__(256) void embed_mfma(
    const __hip_bfloat16* __restrict__ A, const __hip_bfloat16* __restrict__ Bw,
    const float* __restrict__ b_e, const float* __restrict__ pos,
    float* __restrict__ h_e, __hip_bfloat16* __restrict__ heb) {
    __shared__ __align__(16) char lds[16384];
    char* As = lds; char* Bs = lds + 8192;
    int tid = threadIdx.x, lane = tid & 63, wv = tid >> 6;
    int lq = lane >> 4, lr = lane & 15;
    int m0 = blockIdx.y * 64, n0 = blockIdx.x * 64;
    int wm = (wv >> 1) * 32, wn = (wv & 1) * 32;
    f32x4 acc[2][2] = {};
    for (int kt = 0; kt < 5; kt++) {
        int k0b = kt * 128;
        stage64((const char*)A  + (size_t)m0 * 640 + k0b, 640, As, wv, lane);
        stage64((const char*)Bw + (size_t)n0 * 640 + k0b, 640, Bs, wv, lane);
        __syncthreads();
#pragma unroll
        for (int h = 0; h < 2; h++) {
            bf16x8 a0 = ldfrag(As, wm + lr,      h * 4 + lq);
            bf16x8 a1 = ldfrag(As, wm + 16 + lr, h * 4 + lq);
            bf16x8 b0 = ldfrag(Bs, wn + lr,      h * 4 + lq);
            bf16x8 b1 = ldfrag(Bs, wn + 16 + lr, h * 4 + lq);
            acc[0][0] = MFMA_16x16x32_BF16(a0, b0, acc[0][0], 0, 0, 0);
            acc[0][1] = MFMA_16x16x32_BF16(a0, b1, acc[0][1], 0, 0, 0);
            acc[1][0] = MFMA_16x16x32_BF16(a1, b0, acc[1][0], 0, 0, 0);
            acc[1][1] = MFMA_16x16x32_BF16(a1, b1, acc[1][1], 0, 0, 0);
        }
        __syncthreads();
    }
#pragma unroll
    for (int mi = 0; mi < 2; mi++)
#pragma unroll
        for (int ni = 0; ni < 2; ni++)
#pragma unroll
            for (int reg = 0; reg < 4; reg++) {
                int m = m0 + wm + mi * 16 + lq * 4 + reg;
                int n = n0 + wn + ni * 16 + lr;
                int t = m % 96;
                float x = acc[mi][ni][reg] + b_e[n] + pos[t * KD + n];
                x = x > 0.f ? x : (__expf(x) - 1.f);
                h_e[(size_t)m * KD + n] = x;
                heb[(size_t)m * KD + n] = __float2bfloat16(x);
            }
}

// ---------------- fused key/qry: key=c2*(he@W_a^T), qry=c2*(he@V_a^T); K=960 -------
__global__ __launch_bounds__(256) void kq_mfma(
    const __hip_bfloat16* __restrict__ A, const __hip_bfloat16* __restrict__ B1,
    const __hip_bfloat16* __restrict__ B2,
    float* __restrict__ keyv, float* __restrict__ qryv) {
    __shared__ __align__(16) char lds[24576];
    char* As = lds; char* B1s = lds + 8192; char* B2s = lds + 16384;
    int tid = threadIdx.x, lane = tid & 63, wv = tid >> 6;
    int lq = lane >> 4, lr = lane & 15;
    int m0 = blockIdx.y * 64, n0 = blockIdx.x * 64;
    int wm = (wv >> 1) * 32, wn = (wv & 1) * 32;
    f32x4 aK[2][2] = {}, aQ[2][2] = {};
    for (int kt = 0; kt < 15; kt++) {
        int k0b = kt * 128;
        stage64((const char*)A  + (size_t)m0 * 1920 + k0b, 1920, As, wv, lane);
        stage64((const char*)B1 + (size_t)n0 * 1920 + k0b, 1920, B1s, wv, lane);
        stage64((const char*)B2 + (size_t)n0 * 1920 + k0b, 1920, B2s, wv, lane);
        __syncthreads();
#pragma unroll
        for (int h = 0; h < 2; h++) {
            bf16x8 a0  = ldfrag(As,  wm + lr,      h * 4 + lq);
            bf16x8 a1  = ldfrag(As,  wm + 16 + lr, h * 4 + lq);
            bf16x8 b10 = ldfrag(B1s, wn + lr,      h * 4 + lq);
            bf16x8 b11 = ldfrag(B1s, wn + 16 + lr, h * 4 + lq);
            bf16x8 b20 = ldfrag(B2s, wn + lr,      h * 4 + lq);
            bf16x8 b21 = ldfrag(B2s, wn + 16 + lr, h * 4 + lq);
            aK[0][0] = MFMA_16x16x32_BF16(a0, b10, aK[0][0], 0, 0, 0);
            aK[0][1] = MFMA_16x16x32_BF16(a0, b11, aK[0][1], 0, 0, 0);
            aK[1][0] = MFMA_16x16x32_BF16(a1, b10, aK[1][0], 0, 0, 0);
            aK[1][1] = MFMA_16x16x32_BF16(a1, b11, aK[1][1], 0, 0, 0);
            aQ[0][0] = MFMA_16x16x32_BF16(a0, b20, aQ[0][0], 0, 0, 0);
            aQ[0][1] = MFMA_16x16x32_BF16(a0, b21, aQ[0][1], 0, 0, 0);
            aQ[1][0] = MFMA_16x16x32_BF16(a1, b20, aQ[1][0], 0, 0, 0);
            aQ[1][1] = MFMA_16x16x32_BF16(a1, b21, aQ[1][1], 0, 0, 0);
        }
        __syncthreads();
    }
    const float c2 = 2.885390081777927f;  // 2*log2(e): pre-scale for attn exp2
#pragma unroll
    for (int mi = 0; mi < 2; mi++)
#pragma unroll
        for (int ni = 0; ni < 2; ni++)
#pragma unroll
            for (int reg = 0; reg < 4; reg++) {
                int m = m0 + wm + mi * 16 + lq * 4 + reg;
                int n = n0 + wn + ni * 16 + lr;
                keyv[(size_t)m * KD + n] = aK[mi][ni][reg] * c2;
                qryv[(size_t)m * KD + n] = aQ[mi][ni][reg] * c2;
            }
}

// ---------------- fused attention ----------------
// logit_ij = -sum_d 2*w_d*rcp(exp2(key'_jd + qry'_id)+1)   (softmax-equivalent)
// one block per (b, 2 query rows); 512 threads = 8 waves.
__global__ __launch_bounds__(512) void attn_kernel(
    const float* __restrict__ key_v, const float* __restrict__ qry_v,
    const float* __restrict__ h_e, const float* __restrict__ w_a,
    float* __restrict__ h_a) {
    __shared__ float logit_s[2][96];
    int b = blockIdx.x / 48;
    int i0 = (blockIdx.x % 48) * 2;
    int tid = threadIdx.x;
    int lane = tid & 63;
    int wv = tid >> 6;  // 8 waves

    float wr[15], q0[15], q1[15];
    const float* qb = qry_v + ((size_t)b * 96 + i0) * KD;
#pragma unroll
    for (int s = 0; s < 15; s++) {
        int d = s * 64 + lane;
        wr[s] = 2.f * w_a[d];
        q0[s] = qb[d];
        q1[s] = qb[KD + d];
    }

    for (int j = wv; j < 96; j += 8) {
        const float* kp = key_v + ((size_t)b * 96 + j) * KD;
        float s0 = 0.f, s1 = 0.f;
#pragma unroll
        for (int s = 0; s < 15; s++) {
            float kd = kp[s * 64 + lane];
            float r0 = __builtin_amdgcn_rcpf(exp2f(kd + q0[s]) + 1.f);
            float r1 = __builtin_amdgcn_rcpf(exp2f(kd + q1[s]) + 1.f);
            s0 = __builtin_fmaf(wr[s], r0, s0);
            s1 = __builtin_fmaf(wr[s], r1, s1);
        }
#pragma unroll
        for (int off = 32; off; off >>= 1) {
            s0 += __shfl_down(s0, off);
            s1 += __shfl_down(s1, off);
        }
        if (lane == 0) { logit_s[0][j] = -s0; logit_s[1][j] = -s1; }
    }
    __syncthreads();

    if (wv < 2) {
        float x0 = logit_s[wv][lane];
        float x1 = (lane < 32) ? logit_s[wv][lane + 64] : -1e30f;
        float mx = fmaxf(x0, x1);
#pragma unroll
        for (int off = 32; off; off >>= 1) mx = fmaxf(mx, __shfl_xor(mx, off));
        float e0 = __expf(x0 - mx);
        float e1 = (lane < 32) ? __expf(x1 - mx) : 0.f;
        float sm = e0 + e1;
#pragma unroll
        for (int off = 32; off; off >>= 1) sm += __shfl_xor(sm, off);
        float inv = __fdividef(1.f, sm);
        logit_s[wv][lane] = e0 * inv;
        if (lane < 32) logit_s[wv][lane + 64] = e1 * inv;
    }
    __syncthreads();

    for (int d = tid; d < KD; d += 512) {
        const float* hp = h_e + (size_t)b * 96 * KD + d;
        float a0 = 0.f, a1 = 0.f;
#pragma unroll 4
        for (int j = 0; j < 96; j++) {
            float he = hp[(size_t)j * KD];
            a0 += logit_s[0][j] * he;
            a1 += logit_s[1][j] * he;
        }
        float* op = h_a + ((size_t)b * 96 + i0) * KD + d;
        op[0] = a0; op[KD] = a1;
    }
}

// ---------------- temporal decay ----------------
__global__ __launch_bounds__(256) void decay_kernel(
    const float* __restrict__ h_a, const float* __restrict__ M,
    const float* __restrict__ DF, const float* __restrict__ W_td,
    const float* __restrict__ b_td, float* __restrict__ h_r) {
    int idx = blockIdx.x * 256 + threadIdx.x;
    if (idx >= BT * KD) return;
    int bt = idx / KD, kd = idx % KD;
    int d = kd % 96;
    int t = bt % 96;
    float m = M[bt * 96 + d];
    float dl = DF[bt * 96 + d];
    float g = __expf(-fmaxf(dl * W_td[kd] + b_td[kd], 0.f));
    int tsrc = t - (int)dl + 1;
    float ha = h_a[idx];
    float hf = h_a[(size_t)(bt - t + tsrc) * KD + kd];
    h_r[idx] = m * ha + (1.f - m) * (g * hf + (1.f - g) * ha);
}

// ---------------- imputation ----------------
__global__ __launch_bounds__(256) void imput_kernel(
    const float* __restrict__ h_r, const float* __restrict__ W_imp,
    const float* __restrict__ b_imp, float* __restrict__ imput) {
    int idx = blockIdx.x * 256 + threadIdx.x;
    if (idx >= BT * 96) return;
    int bt = idx / 96, d = idx % 96;
    float s = b_imp[d];
#pragma unroll
    for (int k = 0; k < KREP; k++)
        s += W_imp[d * KD + k * 96 + d] * h_r[(size_t)bt * KD + k * 96 + d];
    imput[idx] = s;
}

// ---------------- dense interpolation ----------------
__global__ __launch_bounds__(256) void vinterp_kernel(
    const float* __restrict__ h_r, float* __restrict__ v) {
    int idx = blockIdx.x * 256 + threadIdx.x;
    if (idx >= NB * KD) return;
    int b = idx / KD, kd = idx % KD;
    const float* hp = h_r + (size_t)b * 96 * KD + kd;
    float a0 = 0.f, a1 = 0.f, a2 = 0.f;
    for (int t = 0; t < 96; t++) {
        float h = hp[(size_t)t * KD];
        float p = 3.f * (t + 1) * (1.f / 96.f);
        float w0 = 1.f - fabsf(p - 1.f) * (1.f / 3.f);
        float w1 = 1.f - fabsf(p - 2.f) * (1.f / 3.f);
        float w2 = 1.f - fabsf(p - 3.f) * (1.f / 3.f);
        a0 += w0 * w0 * h; a1 += w1 * w1 * h; a2 += w2 * w2 * h;
    }
    float* vp = v + (size_t)b * 2880 + kd * 3;
    vp[0] = a0; vp[1] = a1; vp[2] = a2;
}

// ---------------- final FC ----------------
__global__ __launch_bounds__(64) void fc_kernel(
    const float* __restrict__ v, const float* __restrict__ W_fc,
    const float* __restrict__ b_fc, float* __restrict__ out) {
    int b = blockIdx.x / 10, o = blockIdx.x % 10;
    int lane = threadIdx.x;
    const float* vp = v + (size_t)b * 2880;
    const float* wp = W_fc + (size_t)o * 2880;
    float s = 0.f;
    for (int j = lane; j < 2880; j += 64) s += vp[j] * wp[j];
#pragma unroll
    for (int off = 32; off; off >>= 1) s += __shfl_down(s, off);
    if (lane == 0) out[b * 10 + o] = s + b_fc[o];
}

extern "C" void kernel_launch(void* const* d_in, const int* in_sizes, int n_in,
                              void* d_out, int out_size, void* d_ws, size_t ws_size,
                              hipStream_t stream) {
    const float* X    = (const float*)d_in[0];
    const float* M    = (const float*)d_in[1];
    const float* DF   = (const float*)d_in[2];
    const float* W_e  = (const float*)d_in[3];
    const float* b_e  = (const float*)d_in[4];
    const float* pos  = (const float*)d_in[5];
    const float* W_a  = (const float*)d_in[6];
    const float* V_a  = (const float*)d_in[7];
    const float* w_a  = (const float*)d_in[8];
    const float* W_td = (const float*)d_in[9];
    const float* b_td = (const float*)d_in[10];
    const float* W_imp= (const float*)d_in[11];
    const float* b_imp= (const float*)d_in[12];
    const float* W_fc = (const float*)d_in[13];
    const float* b_fc = (const float*)d_in[14];

    float* out   = (float*)d_out;         // (16,10)
    float* imput = (float*)d_out + 160;   // (16,96,96)

    // workspace layout (30.2 MB, lifetime-overlapped)
    float* f0 = (float*)d_ws;             // h_e fp32
    float* f1 = f0 + (size_t)BT * KD;     // keyv  -> hr ; head doubles as We_bf16
    float* f2 = f1 + (size_t)BT * KD;     // qryv  -> vv ; head doubles as inp_bf16
    float* f3 = f2 + (size_t)BT * KD;     // ha
    __hip_bfloat16* heb  = (__hip_bfloat16*)(f3 + (size_t)BT * KD);
    __hip_bfloat16* Wab  = heb + (size_t)BT * KD;
    __hip_bfloat16* Vab  = Wab + (size_t)KD * KD;
    __hip_bfloat16* Web  = (__hip_bfloat16*)f1;   // dead before keyv written
    __hip_bfloat16* inpb = (__hip_bfloat16*)f2;   // dead before qryv written

    concat_bf16_kernel<<<(BT * 320 + 255) / 256, 256, 0, stream>>>(X, M, DF, inpb);
    cvt_pad_kernel<<<(960 * 320 + 255) / 256, 256, 0, stream>>>(W_e, Web, 960, 288, 320);
    cvt_pad_kernel<<<(KD * KD + 255) / 256, 256, 0, stream>>>(W_a, Wab, 960, 960, 960);
    cvt_pad_kernel<<<(KD * KD + 255) / 256, 256, 0, stream>>>(V_a, Vab, 960, 960, 960);

    embed_mfma<<<dim3(15, 24), 256, 0, stream>>>(inpb, Web, b_e, pos, f0, heb);
    kq_mfma<<<dim3(15, 24), 256, 0, stream>>>(heb, Wab, Vab, f1, f2);
    attn_kernel<<<NB * 48, 512, 0, stream>>>(f1, f2, f0, w_a, f3);
    decay_kernel<<<(BT * KD + 255) / 256, 256, 0, stream>>>(f3, M, DF, W_td, b_td, f1);
    imput_kernel<<<(BT * 96 + 255) / 256, 256, 0, stream>>>(f1, W_imp, b_imp, imput);
    vinterp_kernel<<<(NB * KD + 255) / 256, 256, 0, stream>>>(f1, f2);
    fc_kernel<<<160, 64, 0, stream>>>(f2, W_fc, b_fc, out);
}

// Round 4
// 118.827 us; speedup vs baseline: 3.3580x; 1.3419x over previous
//
#include <hip/hip_runtime.h>
#include <hip/hip_bf16.h>

#define KD 960
#define BT 1536   // 16*96
#define NB 16

typedef __attribute__((ext_vector_type(8))) short bf16x8;
typedef __attribute__((ext_vector_type(4))) float f32x4;

#define MFMA_16x16x32_BF16 __builtin_amdgcn_mfma_f32_16x16x32_bf16

// =============== fused prep: bf16 casts, pads, transposes ===============
// segments: inpb(491520) Web(307200) Wab(921600) Vab(921600) MT(147456) DFT(147456)
__global__ __launch_bounds__(256) void prep_kernel(
    const float* __restrict__ X, const float* __restrict__ M,
    const float* __restrict__ DF, const float* __restrict__ W_e,
    const float* __restrict__ W_a, const float* __restrict__ V_a,
    __hip_bfloat16* __restrict__ inpb, __hip_bfloat16* __restrict__ Web,
    __hip_bfloat16* __restrict__ Wab, __hip_bfloat16* __restrict__ Vab,
    float* __restrict__ MT, float* __restrict__ DFT) {
    int idx = blockIdx.x * 256 + threadIdx.x;
    if (idx < 491520) {               // inp = [X,M,DF,0pad] as (BT,320) bf16
        int m = idx / 320, j = idx % 320;
        float v = 0.f;
        if (j < 96)       v = X[m * 96 + j];
        else if (j < 192) v = M[m * 96 + (j - 96)];
        else if (j < 288) v = DF[m * 96 + (j - 192)];
        inpb[idx] = __float2bfloat16(v);
        return;
    }
    idx -= 491520;
    if (idx < 307200) {               // W_e (960,288) -> (960,320) bf16
        int r = idx / 320, c = idx % 320;
        Web[idx] = __float2bfloat16(c < 288 ? W_e[r * 288 + c] : 0.f);
        return;
    }
    idx -= 307200;
    if (idx < 921600) { Wab[idx] = __float2bfloat16(W_a[idx]); return; }
    idx -= 921600;
    if (idx < 921600) { Vab[idx] = __float2bfloat16(V_a[idx]); return; }
    idx -= 921600;
    if (idx < 147456) {               // MT[b][d][t] = M[b][t][d]
        int b = idx / 9216, r = idx % 9216, d = r / 96, t = r % 96;
        MT[idx] = M[(b * 96 + t) * 96 + d];
        return;
    }
    idx -= 147456;
    if (idx < 147456) {
        int b = idx / 9216, r = idx % 9216, d = r / 96, t = r % 96;
        DFT[idx] = DF[(b * 96 + t) * 96 + d];
    }
}

// =============== MFMA staging helpers (m97 pattern, XOR-swizzled) ===============
// 64-row x 64-bf16 (128B/row) tile; linear LDS dest, inverse-swizzled global src.
__device__ __forceinline__ void stage64(const char* gRow0, int ldbytes,
                                        char* ldsTile, int wv, int lane) {
#pragma unroll
    for (int rd = 0; rd < 2; rd++) {
        int c  = rd * 256 + wv * 64 + lane;
        int r  = c >> 3;
        int sl = c & 7;
        int ss = sl ^ (r & 7);
        const char* g = gRow0 + (size_t)r * ldbytes + ss * 16;
        __builtin_amdgcn_global_load_lds((const void*)g,
            (void*)(ldsTile + rd * 4096 + wv * 1024), 16, 0, 0);
    }
}
// 32-row x 64-bf16 tile (4KB), one load per thread.
__device__ __forceinline__ void stage32(const char* gRow0, int ldbytes,
                                        char* ldsTile, int tid, int wv) {
    int r  = tid >> 3;
    int sl = tid & 7;
    int ss = sl ^ (r & 7);
    const char* g = gRow0 + (size_t)r * ldbytes + ss * 16;
    __builtin_amdgcn_global_load_lds((const void*)g,
        (void*)(ldsTile + wv * 1024), 16, 0, 0);
}
__device__ __forceinline__ bf16x8 ldfrag(const char* lds, int row, int slot) {
    int ss = slot ^ (row & 7);
    return *(const bf16x8*)(lds + row * 128 + ss * 16);
}

// =============== embed: 32x64 tiles, K=320; writes heb + transposed heT ========
__global__ __launch_bounds__(256) void embed_mfma(
    const __hip_bfloat16* __restrict__ A, const __hip_bfloat16* __restrict__ Bw,
    const float* __restrict__ b_e, const float* __restrict__ pos,
    __hip_bfloat16* __restrict__ heb, __hip_bfloat16* __restrict__ heT) {
    __shared__ __align__(16) char lds[12288];
    char* As = lds; char* Bs = lds + 4096;
    int tid = threadIdx.x, lane = tid & 63, wv = tid >> 6;
    int lq = lane >> 4, lr = lane & 15;
    int m0 = blockIdx.y * 32, n0 = blockIdx.x * 64;
    int wm = (wv >> 1) * 16, wn = (wv & 1) * 32;
    f32x4 acc[2] = {};
    for (int kt = 0; kt < 5; kt++) {
        int k0b = kt * 128;
        stage32((const char*)A + (size_t)m0 * 640 + k0b, 640, As, tid, wv);
        stage64((const char*)Bw + (size_t)n0 * 640 + k0b, 640, Bs, wv, lane);
        __syncthreads();
#pragma unroll
        for (int h = 0; h < 2; h++) {
            bf16x8 a  = ldfrag(As, wm + lr, h * 4 + lq);
            bf16x8 b0 = ldfrag(Bs, wn + lr,      h * 4 + lq);
            bf16x8 b1 = ldfrag(Bs, wn + 16 + lr, h * 4 + lq);
            acc[0] = MFMA_16x16x32_BF16(a, b0, acc[0], 0, 0, 0);
            acc[1] = MFMA_16x16x32_BF16(a, b1, acc[1], 0, 0, 0);
        }
        __syncthreads();
    }
    int mbase = m0 + wm + lq * 4;
    int b = mbase / 96, t0 = mbase % 96;
#pragma unroll
    for (int ni = 0; ni < 2; ni++) {
        int n = n0 + wn + ni * 16 + lr;
        float bn = b_e[n];
        ushort4 pk;
#pragma unroll
        for (int reg = 0; reg < 4; reg++) {
            int t = t0 + reg;
            float x = acc[ni][reg] + bn + pos[t * KD + n];
            x = x > 0.f ? x : (__expf(x) - 1.f);
            __hip_bfloat16 hv = __float2bfloat16(x);
            heb[(size_t)(mbase + reg) * KD + n] = hv;
            ((unsigned short*)&pk)[reg] = *(unsigned short*)&hv;
        }
        *(ushort4*)((char*)heT + (((size_t)b * 960 + n) * 96 + t0) * 2) = pk;
    }
}

// =============== fused key/qry: 32x64 tiles, K=960, c2-scaled ==================
__global__ __launch_bounds__(256) void kq_mfma(
    const __hip_bfloat16* __restrict__ A, const __hip_bfloat16* __restrict__ B1,
    const __hip_bfloat16* __restrict__ B2,
    float* __restrict__ keyv, float* __restrict__ qryv) {
    __shared__ __align__(16) char lds[20480];
    char* As = lds; char* B1s = lds + 4096; char* B2s = lds + 12288;
    int tid = threadIdx.x, lane = tid & 63, wv = tid >> 6;
    int lq = lane >> 4, lr = lane & 15;
    int m0 = blockIdx.y * 32, n0 = blockIdx.x * 64;
    int wm = (wv >> 1) * 16, wn = (wv & 1) * 32;
    f32x4 aK[2] = {}, aQ[2] = {};
    for (int kt = 0; kt < 15; kt++) {
        int k0b = kt * 128;
        stage32((const char*)A + (size_t)m0 * 1920 + k0b, 1920, As, tid, wv);
        stage64((const char*)B1 + (size_t)n0 * 1920 + k0b, 1920, B1s, wv, lane);
        stage64((const char*)B2 + (size_t)n0 * 1920 + k0b, 1920, B2s, wv, lane);
        __syncthreads();
#pragma unroll
        for (int h = 0; h < 2; h++) {
            bf16x8 a   = ldfrag(As,  wm + lr, h * 4 + lq);
            bf16x8 b10 = ldfrag(B1s, wn + lr,      h * 4 + lq);
            bf16x8 b11 = ldfrag(B1s, wn + 16 + lr, h * 4 + lq);
            bf16x8 b20 = ldfrag(B2s, wn + lr,      h * 4 + lq);
            bf16x8 b21 = ldfrag(B2s, wn + 16 + lr, h * 4 + lq);
            aK[0] = MFMA_16x16x32_BF16(a, b10, aK[0], 0, 0, 0);
            aK[1] = MFMA_16x16x32_BF16(a, b11, aK[1], 0, 0, 0);
            aQ[0] = MFMA_16x16x32_BF16(a, b20, aQ[0], 0, 0, 0);
            aQ[1] = MFMA_16x16x32_BF16(a, b21, aQ[1], 0, 0, 0);
        }
        __syncthreads();
    }
    const float c2 = 2.885390081777927f;  // 2*log2(e)
    int mbase = m0 + wm + lq * 4;
#pragma unroll
    for (int ni = 0; ni < 2; ni++) {
        int n = n0 + wn + ni * 16 + lr;
#pragma unroll
        for (int reg = 0; reg < 4; reg++) {
            keyv[(size_t)(mbase + reg) * KD + n] = aK[ni][reg] * c2;
            qryv[(size_t)(mbase + reg) * KD + n] = aQ[ni][reg] * c2;
        }
    }
}

// =============== attention logits + softmax -> S (bf16 probs) ==================
// logit_ij = -sum_d 2*w_d*rcp(exp2(key'_jd + qry'_id)+1)  (softmax-equivalent)
__global__ __launch_bounds__(512, 4) void attn_kernel(
    const float* __restrict__ key_v, const float* __restrict__ qry_v,
    const float* __restrict__ w_a, __hip_bfloat16* __restrict__ S) {
    __shared__ float logit_s[2][96];
    int b = blockIdx.x / 48;
    int i0 = (blockIdx.x % 48) * 2;
    int tid = threadIdx.x;
    int lane = tid & 63;
    int wv = tid >> 6;  // 8 waves

    float wr[15], q0[15], q1[15];
    const float* qb = qry_v + ((size_t)b * 96 + i0) * KD;
#pragma unroll
    for (int s = 0; s < 15; s++) {
        int d = s * 64 + lane;
        wr[s] = 2.f * w_a[d];
        q0[s] = qb[d];
        q1[s] = qb[KD + d];
    }

    for (int j = wv; j < 96; j += 8) {
        const float* kp = key_v + ((size_t)b * 96 + j) * KD;
        float s0 = 0.f, s1 = 0.f;
#pragma unroll
        for (int s = 0; s < 15; s++) {
            float kd = kp[s * 64 + lane];
            float r0 = __builtin_amdgcn_rcpf(exp2f(kd + q0[s]) + 1.f);
            float r1 = __builtin_amdgcn_rcpf(exp2f(kd + q1[s]) + 1.f);
            s0 = __builtin_fmaf(wr[s], r0, s0);
            s1 = __builtin_fmaf(wr[s], r1, s1);
        }
#pragma unroll
        for (int off = 32; off; off >>= 1) {
            s0 += __shfl_down(s0, off);
            s1 += __shfl_down(s1, off);
        }
        if (lane == 0) { logit_s[0][j] = -s0; logit_s[1][j] = -s1; }
    }
    __syncthreads();

    if (wv < 2) {
        float x0 = logit_s[wv][lane];
        float x1 = (lane < 32) ? logit_s[wv][lane + 64] : -1e30f;
        float mx = fmaxf(x0, x1);
#pragma unroll
        for (int off = 32; off; off >>= 1) mx = fmaxf(mx, __shfl_xor(mx, off));
        float e0 = __expf(x0 - mx);
        float e1 = (lane < 32) ? __expf(x1 - mx) : 0.f;
        float sm = e0 + e1;
#pragma unroll
        for (int off = 32; off; off >>= 1) sm += __shfl_xor(sm, off);
        float inv = __fdividef(1.f, sm);
        logit_s[wv][lane] = e0 * inv;
        if (lane < 32) logit_s[wv][lane + 64] = e1 * inv;
    }
    __syncthreads();

    if (tid < 192) {
        int r = tid / 96, j = tid % 96;
        S[((size_t)b * 96 + i0 + r) * 96 + j] = __float2bfloat16(logit_s[r][j]);
    }
}

// =============== h_aT = heT @ S^T  (NT-form, per-b 960x96x96), LDS-free ========
// one wave per block: 16 d-rows x 96 i-cols
__global__ __launch_bounds__(64) void hat_mfma(
    const __hip_bfloat16* __restrict__ heT, const __hip_bfloat16* __restrict__ S,
    float* __restrict__ h_aT) {
    int b = blockIdx.x / 60;
    int d0 = (blockIdx.x % 60) * 16;
    int lane = threadIdx.x, lq = lane >> 4, lr = lane & 15;
    const char* Ab = (const char*)heT + ((size_t)b * 960 + d0) * 192;
    const char* Bb = (const char*)S + (size_t)b * 96 * 192;
    f32x4 acc[6] = {};
#pragma unroll
    for (int kt = 0; kt < 3; kt++) {
        bf16x8 a = *(const bf16x8*)(Ab + (size_t)lr * 192 + kt * 64 + lq * 16);
#pragma unroll
        for (int ni = 0; ni < 6; ni++) {
            bf16x8 bf = *(const bf16x8*)(Bb + (size_t)(ni * 16 + lr) * 192 + kt * 64 + lq * 16);
            acc[ni] = MFMA_16x16x32_BF16(a, bf, acc[ni], 0, 0, 0);
        }
    }
#pragma unroll
    for (int ni = 0; ni < 6; ni++)
#pragma unroll
        for (int reg = 0; reg < 4; reg++)
            h_aT[((size_t)b * 960 + d0 + lq * 4 + reg) * 96 + ni * 16 + lr] = acc[ni][reg];
}

// =============== temporal decay + dense-interp (fused, transposed space) =======
__global__ __launch_bounds__(128) void decayv_kernel(
    const float* __restrict__ h_aT, const float* __restrict__ MT,
    const float* __restrict__ DFT, const float* __restrict__ W_td,
    const float* __restrict__ b_td, float* __restrict__ h_rT,
    float* __restrict__ v) {
    __shared__ float red[6];
    int b = blockIdx.x / 960, kd = blockIdx.x % 960;
    int t = threadIdx.x;
    int lane = t & 63, wv = t >> 6;
    int d = kd % 96;
    float p0 = 0.f, p1 = 0.f, p2 = 0.f;
    if (t < 96) {
        const float* har = h_aT + ((size_t)b * 960 + kd) * 96;
        float ha = har[t];
        float m  = MT[((size_t)b * 96 + d) * 96 + t];
        float df = DFT[((size_t)b * 96 + d) * 96 + t];
        float g  = __expf(-fmaxf(df * W_td[kd] + b_td[kd], 0.f));
        int tsrc = t - (int)df + 1;
        float hf = har[tsrc];
        float hr = m * ha + (1.f - m) * (g * hf + (1.f - g) * ha);
        h_rT[((size_t)b * 960 + kd) * 96 + t] = hr;
        float p  = 3.f * (t + 1) * (1.f / 96.f);
        float w0 = 1.f - fabsf(p - 1.f) * (1.f / 3.f);
        float w1 = 1.f - fabsf(p - 2.f) * (1.f / 3.f);
        float w2 = 1.f - fabsf(p - 3.f) * (1.f / 3.f);
        p0 = w0 * w0 * hr; p1 = w1 * w1 * hr; p2 = w2 * w2 * hr;
    }
#pragma unroll
    for (int off = 32; off; off >>= 1) {
        p0 += __shfl_down(p0, off);
        p1 += __shfl_down(p1, off);
        p2 += __shfl_down(p2, off);
    }
    if (lane == 0) { red[wv * 3 + 0] = p0; red[wv * 3 + 1] = p1; red[wv * 3 + 2] = p2; }
    __syncthreads();
    if (t == 0) {
        float* vp = v + (size_t)b * 2880 + kd * 3;
        vp[0] = red[0] + red[3];
        vp[1] = red[1] + red[4];
        vp[2] = red[2] + red[5];
    }
}

// =============== imputation (reads h_rT coalesced, scattered write) ============
__global__ __launch_bounds__(128) void imput_kernel(
    const float* __restrict__ h_rT, const float* __restrict__ W_imp,
    const float* __restrict__ b_imp, float* __restrict__ imput) {
    int b = blockIdx.x / 96, d = blockIdx.x % 96;
    int t = threadIdx.x;
    if (t >= 96) return;
    float s = b_imp[d];
#pragma unroll
    for (int k = 0; k < 10; k++)
        s += W_imp[d * KD + k * 96 + d] * h_rT[((size_t)b * 960 + k * 96 + d) * 96 + t];
    imput[((size_t)b * 96 + t) * 96 + d] = s;
}

// =============== final FC ======================================================
__global__ __launch_bounds__(64) void fc_kernel(
    const float* __restrict__ v, const float* __restrict__ W_fc,
    const float* __restrict__ b_fc, float* __restrict__ out) {
    int b = blockIdx.x / 10, o = blockIdx.x % 10;
    int lane = threadIdx.x;
    const float* vp = v + (size_t)b * 2880;
    const float* wp = W_fc + (size_t)o * 2880;
    float s = 0.f;
    for (int j = lane; j < 2880; j += 64) s += vp[j] * wp[j];
#pragma unroll
    for (int off = 32; off; off >>= 1) s += __shfl_down(s, off);
    if (lane == 0) out[b * 10 + o] = s + b_fc[o];
}

extern "C" void kernel_launch(void* const* d_in, const int* in_sizes, int n_in,
                              void* d_out, int out_size, void* d_ws, size_t ws_size,
                              hipStream_t stream) {
    const float* X    = (const float*)d_in[0];
    const float* M    = (const float*)d_in[1];
    const float* DF   = (const float*)d_in[2];
    const float* W_e  = (const float*)d_in[3];
    const float* b_e  = (const float*)d_in[4];
    const float* pos  = (const float*)d_in[5];
    const float* W_a  = (const float*)d_in[6];
    const float* V_a  = (const float*)d_in[7];
    const float* w_a  = (const float*)d_in[8];
    const float* W_td = (const float*)d_in[9];
    const float* b_td = (const float*)d_in[10];
    const float* W_imp= (const float*)d_in[11];
    const float* b_imp= (const float*)d_in[12];
    const float* W_fc = (const float*)d_in[13];
    const float* b_fc = (const float*)d_in[14];

    float* out   = (float*)d_out;         // (16,10)
    float* imput = (float*)d_out + 160;   // (16,96,96)

    char* w = (char*)d_ws;
    __hip_bfloat16* inpb = (__hip_bfloat16*)(w);             //   983,040
    __hip_bfloat16* Web  = (__hip_bfloat16*)(w + 983040);    //   614,400
    __hip_bfloat16* Wab  = (__hip_bfloat16*)(w + 1597440);   // 1,843,200
    __hip_bfloat16* Vab  = (__hip_bfloat16*)(w + 3440640);   // 1,843,200
    __hip_bfloat16* heb  = (__hip_bfloat16*)(w + 5283840);   // 2,949,120
    __hip_bfloat16* heT  = (__hip_bfloat16*)(w + 8232960);   // 2,949,120
    __hip_bfloat16* Sp   = (__hip_bfloat16*)(w + 11182080);  //   294,912
    float* MT   = (float*)(w + 11476992);                    //   589,824
    float* DFT  = (float*)(w + 12066816);                    //   589,824
    float* keyv = (float*)(w + 12656640);                    // 5,898,240
    float* qryv = (float*)(w + 18554880);                    // 5,898,240
    float* h_aT = keyv;   // dead after attn
    float* h_rT = qryv;   // dead after attn
    float* vv   = (float*)(w + 24453120);                    //   184,320 -> 24.6MB total

    prep_kernel<<<11472, 256, 0, stream>>>(X, M, DF, W_e, W_a, V_a,
                                           inpb, Web, Wab, Vab, MT, DFT);
    embed_mfma<<<dim3(15, 48), 256, 0, stream>>>(inpb, Web, b_e, pos, heb, heT);
    kq_mfma<<<dim3(15, 48), 256, 0, stream>>>(heb, Wab, Vab, keyv, qryv);
    attn_kernel<<<NB * 48, 512, 0, stream>>>(keyv, qryv, w_a, Sp);
    hat_mfma<<<NB * 60, 64, 0, stream>>>(heT, Sp, h_aT);
    decayv_kernel<<<NB * 960, 128, 0, stream>>>(h_aT, MT, DFT, W_td, b_td, h_rT, vv);
    imput_kernel<<<NB * 96, 128, 0, stream>>>(h_rT, W_imp, b_imp, imput);
    fc_kernel<<<160, 64, 0, stream>>>(vv, W_fc, b_fc, out);
}